// Round 23
// baseline (595.239 us; speedup 1.0000x reference)
//
#include <hip/hip_runtime.h>
#include <hip/hip_bf16.h>

// GCNBlock: TransformerConv(32 heads, dim 8, edge_dim 64) + EdgeResidualLayer
// N=50000, E=400000, D_NODE=256, D_EDGE=64. FP32 in/out, int64 edge_index.
// Internals: bf16 MFMA (16x16x32) with fp32 accumulate.
//
// Round 23: fuse easb production into kct_scatter. Round 22's keir pass
// re-paid the random ea gather it was meant to delete (k2 -20us but total
// +5us). In kct, edge i is in ORIGINAL order: ea read is sequential
// (102MB streaming) and easb[pos] is a full 128B row write (51MB,
// write-combining) -- same bytes, random-read -> seq-read, one launch less.
// Carried: sorted-ea consumers (r22), k4 P-vectorization (r21),
// kv-interleave (r20), fused finalize+P-GEMM in k2 (r18), fragment-major B
// layouts (r15), CSR dst-sort, barrier-free k1/k2, k4 XCD swizzle,
// nt loads, cached stores.

#define N_NODES 50000
#define N_EDGES 400000
#define D_NODE 256
#define D_EDGE 64
#define HEADS 32
#define LRELU 0.01f
#define SEG 16          // dst nodes per k2 block

typedef __hip_bfloat16 bf16;
typedef __attribute__((ext_vector_type(8))) short short8b;          // 8 bf16
typedef __attribute__((ext_vector_type(4))) float f32x4;
typedef __attribute__((ext_vector_type(4))) unsigned short ushort4v;
typedef __attribute__((ext_vector_type(4))) int int4v;

__device__ __forceinline__ float bf2f(bf16 v) { return __bfloat162float(v); }
__device__ __forceinline__ bf16 f2bf(float f) { return __float2bfloat16(f); }
__device__ __forceinline__ float bfraw(unsigned short u) {
    return __uint_as_float(((unsigned int)u) << 16);
}
__device__ __forceinline__ unsigned short rawbf(float f) {
    bf16 t = f2bf(f); return *(unsigned short*)&t;
}
__device__ __forceinline__ float leaky(float v) { return v >= 0.f ? v : LRELU * v; }
__device__ __forceinline__ short8b pack8(const f32x4 a, const f32x4 b) {
    short8b r;
    r[0] = (short)rawbf(a[0]); r[1] = (short)rawbf(a[1]);
    r[2] = (short)rawbf(a[2]); r[3] = (short)rawbf(a[3]);
    r[4] = (short)rawbf(b[0]); r[5] = (short)rawbf(b[1]);
    r[6] = (short)rawbf(b[2]); r[7] = (short)rawbf(b[3]);
    return r;
}

// ---------------- k0: index width detection (1 wave) ----------------
__global__ void k0_detect(const int* __restrict__ ei, int* __restrict__ flags)
{
    const int lane = threadIdx.x;
    const unsigned long long mz = __ballot(ei[2 * lane + 1] == 0);
    if (lane == 0) flags[0] = (__popcll(mz) >= 48) ? 1 : 0;   // 1 => int64
}

__device__ __forceinline__ void load_edge(const int* ei, int f, int i, int& s, int& d)
{
    if (f) {
        const long long* e64 = (const long long*)ei;
        s = (int)e64[i]; d = (int)e64[N_EDGES + i];
    } else {
        s = ei[i]; d = ei[N_EDGES + i];
    }
}

// ---------------- CSR build ----------------
__global__ __launch_bounds__(256) void kcd_degree(
    const int* __restrict__ ei, const int* __restrict__ flags, int* __restrict__ deg)
{
    const int i = blockIdx.x * 256 + threadIdx.x;
    if (i >= N_EDGES) return;
    int s, d; load_edge(ei, flags[0], i, s, d);
    atomicAdd(&deg[d], 1);
}

__global__ __launch_bounds__(1024) void kcs_scan(int* __restrict__ cur)  // deg -> excl. offsets
{
    __shared__ int ps[1024];
    const int t = threadIdx.x;
    const int CHN = (N_NODES + 1023) / 1024;   // 49
    const int base = t * CHN;
    int sum = 0;
    for (int i = 0; i < CHN; ++i) {
        const int n = base + i;
        if (n < N_NODES) sum += cur[n];
    }
    ps[t] = sum;
    __syncthreads();
    for (int off = 1; off < 1024; off <<= 1) {
        const int v = (t >= off) ? ps[t - off] : 0;
        __syncthreads();
        ps[t] += v;
        __syncthreads();
    }
    int excl = (t == 0) ? 0 : ps[t - 1];
    for (int i = 0; i < CHN; ++i) {
        const int n = base + i;
        if (n < N_NODES) {
            const int d = cur[n];
            cur[n] = excl;
            excl += d;
        }
    }
}

// scatter + fused sorted-ea materialization (seq fp32 read -> scattered bf16 row)
__global__ __launch_bounds__(256) void kct_scatter(
    const int* __restrict__ ei, const int* __restrict__ flags, int* __restrict__ cursor,
    const float* __restrict__ ea,
    int* __restrict__ ssort, int* __restrict__ dsort, int* __restrict__ eidsort,
    bf16* __restrict__ easb)
{
    const int i = blockIdx.x * 256 + threadIdx.x;
    if (i >= N_EDGES) return;
    int s, d; load_edge(ei, flags[0], i, s, d);
    const int pos = atomicAdd(&cursor[d], 1);
    ssort[pos] = s; dsort[pos] = d; eidsort[pos] = i;
    // ea row i (fp32, sequential across threads) -> easb row pos (bf16)
    const f32x4* src = (const f32x4*)(ea + (size_t)i * 64);
    bf16* dst = easb + (size_t)pos * 64;
    #pragma unroll
    for (int c = 0; c < 2; ++c) {
        unsigned short tmp[32];
        #pragma unroll
        for (int u = 0; u < 8; ++u) {
            const f32x4 v = __builtin_nontemporal_load(src + c * 8 + u);
            tmp[u * 4 + 0] = rawbf(v[0]); tmp[u * 4 + 1] = rawbf(v[1]);
            tmp[u * 4 + 2] = rawbf(v[2]); tmp[u * 4 + 3] = rawbf(v[3]);
        }
        #pragma unroll
        for (int u = 0; u < 4; ++u)
            *(short8b*)(dst + c * 32 + u * 8) = *(short8b*)&tmp[u * 8];
    }
    // after this kernel: cursor[n] == end offset of node n (inclusive)
}

// ---------------- kT: fragment-major weight layouts (fp32 -> bf16) ----------------
__global__ __launch_bounds__(256) void kT_transpose(
    const float* __restrict__ We, const float* __restrict__ W1, const float* __restrict__ W2,
    const float* __restrict__ Wq, const float* __restrict__ Wk,
    const float* __restrict__ Wv, const float* __restrict__ Ws,
    bf16* __restrict__ WeTf, bf16* __restrict__ W1sdf, bf16* __restrict__ W1eaf,
    bf16* __restrict__ W2Tf, bf16* __restrict__ WT4f)
{
    const int gid = blockIdx.x * 256 + threadIdx.x;
    const int gsz = gridDim.x * 256;
    // WT4f: [m(4)][ct(16)][kc(8)][l(64)][j(8)]  (q,k,v,s; 256x256 each)
    for (int i = gid; i < 4 * 16 * 8 * 512; i += gsz) {
        const int j = i & 7, l = (i >> 3) & 63, kc = (i >> 9) & 7;
        const int ct = (i >> 12) & 15, m = i >> 16;
        const int row = l & 15, kg = l >> 4;
        const int n = ct * 16 + row, k = kc * 32 + kg * 8 + j;
        const float* W = (m == 0) ? Wq : (m == 1) ? Wk : (m == 2) ? Wv : Ws;
        WT4f[i] = f2bf(W[k * 256 + n]);
    }
    // WeTf: [ct(16)][kc(2)][l][j]  (We: 64x256)
    for (int i = gid; i < 16 * 2 * 512; i += gsz) {
        const int j = i & 7, l = (i >> 3) & 63, kc = (i >> 9) & 1, ct = i >> 10;
        const int row = l & 15, kg = l >> 4;
        const int n = ct * 16 + row, k = kc * 32 + kg * 8 + j;
        WeTf[i] = f2bf(We[k * 256 + n]);
    }
    // W1sdf: [m2(2)][ct(4)][kc(8)][l][j]  (W1 rows 0..255 = x_s, 256..511 = x_d)
    for (int i = gid; i < 2 * 4 * 8 * 512; i += gsz) {
        const int j = i & 7, l = (i >> 3) & 63, kc = (i >> 9) & 7;
        const int ct = (i >> 12) & 3, m2 = i >> 14;
        const int row = l & 15, kg = l >> 4;
        const int n = ct * 16 + row;
        const int k = m2 * 256 + kc * 32 + kg * 8 + j;
        W1sdf[i] = f2bf(W1[k * 64 + n]);
    }
    // W1eaf: [ct(4)][kc(2)][l][j]  (W1 rows 512..575 = ea)
    for (int i = gid; i < 4 * 2 * 512; i += gsz) {
        const int j = i & 7, l = (i >> 3) & 63, kc = (i >> 9) & 1, ct = i >> 10;
        const int row = l & 15, kg = l >> 4;
        const int n = ct * 16 + row;
        const int k = 512 + kc * 32 + kg * 8 + j;
        W1eaf[i] = f2bf(W1[k * 64 + n]);
    }
    // W2Tf: [ct(4)][kc(2)][l][j]  (W2: 64x64)
    for (int i = gid; i < 4 * 2 * 512; i += gsz) {
        const int j = i & 7, l = (i >> 3) & 63, kc = (i >> 9) & 1, ct = i >> 10;
        const int row = l & 15, kg = l >> 4;
        const int n = ct * 16 + row, k = kc * 32 + kg * 8 + j;
        W2Tf[i] = f2bf(W2[k * 64 + n]);
    }
}

// ---------------- k1: node linears via MFMA (k|v interleaved out) ----------------
#define X_LD 264
__global__ __launch_bounds__(256) void k1_node_mfma(
    const float* __restrict__ x, const bf16* __restrict__ WT4f,
    const float* __restrict__ bq, const float* __restrict__ bk,
    const float* __restrict__ bv, const float* __restrict__ bs,
    bf16* __restrict__ qo, bf16* __restrict__ kvb,
    bf16* __restrict__ skipb)
{
    __shared__ unsigned short xs[64 * X_LD];   // 33792 B; rows wave-private
    const int tid = threadIdx.x;
    const int n0 = blockIdx.x * 64;
    const int w = tid >> 6, l = tid & 63;
    const int row = l & 15, kg = l >> 4;

    { // stage x tile (fp32 -> bf16), nt loads; wave-private rows
        const int e = tid >> 2, t = tid & 3;
        const int nmine = n0 + e;
        const f32x4* src = (const f32x4*)(x + (size_t)nmine * 256 + t * 64);
        #pragma unroll
        for (int c = 0; c < 4; ++c) {
            unsigned short tmp[16];
            if (nmine < N_NODES) {
                #pragma unroll
                for (int u = 0; u < 4; ++u) {
                    const f32x4 v = __builtin_nontemporal_load(src + c * 4 + u);
                    tmp[u * 4 + 0] = rawbf(v[0]); tmp[u * 4 + 1] = rawbf(v[1]);
                    tmp[u * 4 + 2] = rawbf(v[2]); tmp[u * 4 + 3] = rawbf(v[3]);
                }
            } else {
                #pragma unroll
                for (int u = 0; u < 16; ++u) tmp[u] = 0;
            }
            *(short8b*)&xs[e * X_LD + t * 64 + c * 16]     = *(short8b*)&tmp[0];
            *(short8b*)&xs[e * X_LD + t * 64 + c * 16 + 8] = *(short8b*)&tmp[8];
        }
    }
    // same-wave DS ops are in-order: staging writes precede these reads
    short8b af[8];
    #pragma unroll
    for (int kc = 0; kc < 8; ++kc)
        af[kc] = *(const short8b*)&xs[(w * 16 + row) * X_LD + kc * 32 + kg * 8];

    for (int m = 0; m < 4; ++m) {
        const float* bias = (m == 0) ? bq : (m == 1) ? bk : (m == 2) ? bv : bs;
        #pragma unroll 4
        for (int ct = 0; ct < 16; ++ct) {
            const float bvv = bias[ct * 16 + row];
            f32x4 acc = {bvv, bvv, bvv, bvv};
            #pragma unroll
            for (int kc = 0; kc < 8; ++kc) {
                const short8b bfr = *(const short8b*)(WT4f + (((size_t)((m * 16 + ct) * 8 + kc)) << 9) + l * 8);
                acc = __builtin_amdgcn_mfma_f32_16x16x32_bf16(af[kc], bfr, acc, 0, 0, 0);
            }
            #pragma unroll
            for (int r = 0; r < 4; ++r)   // bounce into this wave's own rows
                xs[(w * 16 + kg * 4 + r) * X_LD + ct * 16 + row] = rawbf(acc[r]);
        }
        { // per-wave cached store: each instruction writes 1KB contiguous
            #pragma unroll
            for (int u = 0; u < 8; ++u) {
                const int flat = u * 64 + l;          // 16B unit in wave's 8KB
                const int node = w * 16 + (flat >> 5);
                const int col8 = (flat & 31) * 8;
                if (n0 + node < N_NODES) {
                    const short8b vdat = *(const short8b*)&xs[node * X_LD + col8];
                    bf16* dp;
                    if (m == 0)      dp = qo    + (size_t)(n0 + node) * 256 + col8;
                    else if (m == 1) dp = kvb   + (size_t)(n0 + node) * 512 + col8;        // k half
                    else if (m == 2) dp = kvb   + (size_t)(n0 + node) * 512 + 256 + col8;  // v half
                    else             dp = skipb + (size_t)(n0 + node) * 256 + col8;
                    *(short8b*)dp = vdat;
                }
            }
        }
        // no barrier: same-wave DS in-order; waves never share rows
    }
}

// ---------------- k2: segment attention + fused finalize + fused P-GEMM ----------------
#define EP_LD 264
__global__ __launch_bounds__(256) void k2_seg(
    const int* __restrict__ ssort, const int* __restrict__ dsort,
    const int* __restrict__ endptr,
    const bf16* __restrict__ easb, const bf16* __restrict__ WeTf,
    const bf16* __restrict__ q, const bf16* __restrict__ kvb,
    const bf16* __restrict__ skipb, const bf16* __restrict__ W1sdf,
    float* __restrict__ out_x, bf16* __restrict__ P)
{
    __shared__ float acc_s[SEG * 256];            // 16 KB msg accumulator
    __shared__ float den_s[SEG * HEADS];          // 2 KB
    __shared__ unsigned short ep_s[64 * EP_LD];   // 33 KB (wave-private rows; reused for xn)
    const int tid = threadIdx.x;
    const int n0 = blockIdx.x * SEG;

    #pragma unroll
    for (int i = 0; i < SEG; ++i) acc_s[i * 256 + tid] = 0.f;
    if (tid < SEG * HEADS - 256) den_s[256 + tid] = 0.f;
    den_s[tid] = 0.f;

    const int start = (n0 == 0) ? 0 : endptr[n0 - 1];
    const int end   = endptr[n0 + SEG - 1];
    __syncthreads();

    const int w = tid >> 6, l = tid & 63;
    const int row = l & 15, kg = l >> 4;
    const float scale = 0.35355339059327373f;   // 1/sqrt(8)

    // each wave free-runs its own 16-edge slices; no barriers in this loop
    for (int sbase = start + w * 16; sbase < end; sbase += 64) {
        const int cnt = min(16, end - sbase);   // >= 1

        // --- A fragments: SEQUENTIAL bf16 loads from sorted easb (no index) ---
        short8b af0 = {0, 0, 0, 0, 0, 0, 0, 0}, af1 = af0;
        if (row < cnt) {
            const bf16* pe = easb + (size_t)(sbase + row) * 64;
            af0 = *(const short8b*)(pe + kg * 8);
            af1 = *(const short8b*)(pe + 32 + kg * 8);
        }

        // --- edge indices for this wave's slice ---
        int sv = 0;
        if (l < 16)      { if (l < cnt)      sv = ssort[sbase + l]; }
        else if (l < 32) { if (l - 16 < cnt) sv = dsort[sbase + (l - 16)]; }

        // --- prefetch k/v slices from interleaved kvb (one 1KB row / edge) ---
        ushort4v kvv[16], vvv[16];
        #pragma unroll
        for (int i = 0; i < 16; ++i) {
            const int s = __shfl(sv, min(i, cnt - 1));
            const bf16* base = kvb + (size_t)s * 512;
            kvv[i] = *(const ushort4v*)(base + l * 4);
            vvv[i] = *(const ushort4v*)(base + 256 + l * 4);
        }
        __builtin_amdgcn_sched_barrier(0);   // pin: all gathers issued

        // --- eproj MFMA into wave-private ep rows (coalesced B) ---
        #pragma unroll 4
        for (int ct = 0; ct < 16; ++ct) {
            f32x4 acc = {0.f, 0.f, 0.f, 0.f};
            const short8b b0 = *(const short8b*)(WeTf + (ct * 2 + 0) * 512 + l * 8);
            const short8b b1 = *(const short8b*)(WeTf + (ct * 2 + 1) * 512 + l * 8);
            acc = __builtin_amdgcn_mfma_f32_16x16x32_bf16(af0, b0, acc, 0, 0, 0);
            acc = __builtin_amdgcn_mfma_f32_16x16x32_bf16(af1, b1, acc, 0, 0, 0);
            #pragma unroll
            for (int r = 0; r < 4; ++r)
                ep_s[(w * 16 + kg * 4 + r) * EP_LD + ct * 16 + row] = rawbf(acc[r]);
        }
        // same-wave LDS write->read is in-order: no barrier needed

        // --- attention (run-compressed); q loaded per run ---
        float macc[4] = {0.f, 0.f, 0.f, 0.f};
        float dacc = 0.f;
        int dprev = -1;
        ushort4v qv = {0, 0, 0, 0};

        #pragma unroll
        for (int i = 0; i < 16; ++i) {
            const int d = __shfl(sv, 16 + min(i, cnt - 1));
            if (d != dprev) {                  // wave-uniform
                if (dprev >= 0) {
                    const int ld = dprev - n0;
                    #pragma unroll
                    for (int t = 0; t < 4; ++t)
                        atomicAdd(&acc_s[ld * 256 + l * 4 + t], macc[t]);
                    if ((l & 1) == 0)
                        atomicAdd(&den_s[ld * HEADS + (l >> 1)], dacc);
                    macc[0] = macc[1] = macc[2] = macc[3] = 0.f;
                    dacc = 0.f;
                }
                qv = *(const ushort4v*)(q + (size_t)d * 256 + l * 4);
                dprev = d;
            }
            const ushort4v ep = *(const ushort4v*)&ep_s[(w * 16 + i) * EP_LD + l * 4];
            float p = 0.f, m4[4];
            #pragma unroll
            for (int t = 0; t < 4; ++t) {
                const float epf = bfraw(ep[t]);
                p = fmaf(bfraw(qv[t]), bfraw(kvv[i][t]) + epf, p);
                m4[t] = bfraw(vvv[i][t]) + epf;
            }
            p += __shfl_xor(p, 1);             // head = l>>1 (2 lanes/head)
            const float ex = (i < cnt) ? __expf(p * scale) : 0.f;
            #pragma unroll
            for (int t = 0; t < 4; ++t) macc[t] = fmaf(m4[t], ex, macc[t]);
            dacc += ex;
        }
        {
            const int ld = dprev - n0;
            #pragma unroll
            for (int t = 0; t < 4; ++t)
                atomicAdd(&acc_s[ld * 256 + l * 4 + t], macc[t]);
            if ((l & 1) == 0)
                atomicAdd(&den_s[ld * HEADS + (l >> 1)], dacc);
        }
    }
    __syncthreads();   // all waves' aggregation done; ep_s free for reuse

    // finalize: x_new = leaky(acc/den + skip) -> out_x fp32;
    // xn bf16 stashed in ep_s rows [node][ch] for the fused P-GEMM.
    #pragma unroll
    for (int u = 0; u < 4; ++u) {
        const int flat4 = u * 256 + tid;        // f32x4 unit; 64 per node
        const int node = flat4 >> 6;
        const int ch4 = flat4 & 63;
        const int n = n0 + node;
        const float den = den_s[node * HEADS + (ch4 >> 1)] + 1e-16f;
        const f32x4 mv = *(const f32x4*)&acc_s[node * 256 + ch4 * 4];
        const ushort4v sk = *(const ushort4v*)(skipb + (size_t)n * 256 + ch4 * 4);
        f32x4 o; ushort4v ob;
        #pragma unroll
        for (int t = 0; t < 4; ++t) {
            const float xn = leaky(mv[t] / den + bfraw(sk[t]));
            o[t] = xn; ob[t] = rawbf(xn);
        }
        *(f32x4*)(out_x + (size_t)n * 256 + ch4 * 4) = o;
        *(ushort4v*)&ep_s[node * EP_LD + ch4 * 4] = ob;
    }
    __syncthreads();

    // fused P-GEMM (was k3b): P[n] = [xn@W1_s | xn@W1_d]; 8 ct tiles / 4 waves
    // P layout (k4-optimized): P[n][m2*64 + row*4 + ct4] -- each k4 lane's 4
    // values are one contiguous 8B ushort4.
    {
        short8b af2[8];
        #pragma unroll
        for (int kc = 0; kc < 8; ++kc)
            af2[kc] = *(const short8b*)&ep_s[row * EP_LD + kc * 32 + kg * 8];
        #pragma unroll
        for (int c2 = 0; c2 < 2; ++c2) {
            const int ct = w * 2 + c2;            // 0..7 over 128 P columns
            const int m2 = ct >> 2, ct4 = ct & 3;
            f32x4 acc = {0.f, 0.f, 0.f, 0.f};
            #pragma unroll
            for (int kc = 0; kc < 8; ++kc) {
                const short8b bfr = *(const short8b*)(W1sdf + ((m2 * 4 + ct4) * 8 + kc) * 512 + l * 8);
                acc = __builtin_amdgcn_mfma_f32_16x16x32_bf16(af2[kc], bfr, acc, 0, 0, 0);
            }
            #pragma unroll
            for (int r = 0; r < 4; ++r)
                P[(size_t)(n0 + kg * 4 + r) * 128 + m2 * 64 + row * 4 + ct4] = f2bf(acc[r]);
        }
    }
}

// ---------------- k4: edge MLP, sequential easb + vectorized P gathers ----------------
__global__ __launch_bounds__(256) void k4_edge_mlp(
    const int* __restrict__ ssort, const int* __restrict__ dsort,
    const int* __restrict__ eidsort,
    const bf16* __restrict__ P, const bf16* __restrict__ easb,
    const bf16* __restrict__ W1eaf, const float* __restrict__ b1,
    const bf16* __restrict__ W2Tf, const float* __restrict__ b2,
    float* __restrict__ out_e)
{
    __shared__ unsigned short h2_s[4][16 * 72];   // 9216 B, wave-private
    const int tid = threadIdx.x;
    const int w = tid >> 6, l = tid & 63;
    const int row = l & 15, kg = l >> 4;

    // bijective XCD swizzle (T1, m204): nwg=6250, q8=781, r8=2
    const int q8 = (N_EDGES / 64) >> 3, r8 = (N_EDGES / 64) & 7;
    const int xcd = blockIdx.x & 7, idx = blockIdx.x >> 3;
    const int bid = (xcd < r8 ? xcd * (q8 + 1) : r8 * (q8 + 1) + (xcd - r8) * q8) + idx;
    const int e0 = bid * 64;
    const int sl = e0 + w * 16 + row;            // this lane's A-row edge (sorted)

    // C-row edge indices via int4 (cr0 16B-aligned: e0 mult of 64)
    const int cr0 = e0 + w * 16 + kg * 4;
    const int4v s4  = *(const int4v*)(ssort + cr0);
    const int4v d4  = *(const int4v*)(dsort + cr0);
    const int4v eg4 = *(const int4v*)(eidsort + cr0);

    // ---- issue all loads up front: 2 easb seq + 8 P ushort4 gathers ----
    const bf16* pe = easb + (size_t)sl * 64;
    const short8b afr0 = *(const short8b*)(pe + kg * 8);
    const short8b afr1 = *(const short8b*)(pe + 32 + kg * 8);

    const unsigned short* Pu = (const unsigned short*)P;
    ushort4v ps4[4], pd4[4];   // ps4[r][ct] = psv[ct][r]
    #pragma unroll
    for (int r = 0; r < 4; ++r) {
        ps4[r] = *(const ushort4v*)(Pu + (size_t)s4[r] * 128 + row * 4);
        pd4[r] = *(const ushort4v*)(Pu + (size_t)d4[r] * 128 + 64 + row * 4);
    }
    __builtin_amdgcn_sched_barrier(0);   // pin: all loads issued before compute

    // ---- GEMM1: ea part only, [16 x 64] @ W1_ea -> [16 x 64] (coalesced B) ----
    f32x4 acc[4];
    #pragma unroll
    for (int ct = 0; ct < 4; ++ct) {
        const float bvv = b1[ct * 16 + row];
        acc[ct] = (f32x4){bvv, bvv, bvv, bvv};
    }
    #pragma unroll
    for (int kc = 0; kc < 2; ++kc) {
        const short8b af = (kc == 0) ? afr0 : afr1;
        #pragma unroll
        for (int ct = 0; ct < 4; ++ct) {
            const short8b bfr = *(const short8b*)(W1eaf + (ct * 2 + kc) * 512 + l * 8);
            acc[ct] = __builtin_amdgcn_mfma_f32_16x16x32_bf16(af, bfr, acc[ct], 0, 0, 0);
        }
    }
    // add precomputed node projections (ps4[r][ct] layout)
    #pragma unroll
    for (int ct = 0; ct < 4; ++ct)
        #pragma unroll
        for (int r = 0; r < 4; ++r)
            acc[ct][r] += bfraw(ps4[r][ct]) + bfraw(pd4[r][ct]);

    // h2 = leaky(acc) -> wave-private LDS bounce (same-wave in-order)
    unsigned short* h2 = h2_s[w];
    #pragma unroll
    for (int ct = 0; ct < 4; ++ct)
        #pragma unroll
        for (int r = 0; r < 4; ++r)
            h2[(kg * 4 + r) * 72 + ct * 16 + row] = rawbf(leaky(acc[ct][r]));

    // ---- GEMM2: [16 x 64] @ W2 -> [16 x 64] (coalesced B) ----
    f32x4 a2[4];
    #pragma unroll
    for (int ct = 0; ct < 4; ++ct) {
        const float bvv = b2[ct * 16 + row];
        a2[ct] = (f32x4){bvv, bvv, bvv, bvv};
    }
    #pragma unroll
    for (int kc = 0; kc < 2; ++kc) {
        const short8b af = *(const short8b*)&h2[row * 72 + kc * 32 + kg * 8];
        #pragma unroll
        for (int ct = 0; ct < 4; ++ct) {
            const short8b bfr = *(const short8b*)(W2Tf + (ct * 2 + kc) * 512 + l * 8);
            a2[ct] = __builtin_amdgcn_mfma_f32_16x16x32_bf16(af, bfr, a2[ct], 0, 0, 0);
        }
    }

    // epilogue: out = leaky(ea + h2@W2+b2); ea residual from sequential easb
    #pragma unroll
    for (int ct = 0; ct < 4; ++ct)
        #pragma unroll
        for (int r = 0; r < 4; ++r) {
            const float eav = bfraw(*(const unsigned short*)(easb + (size_t)(cr0 + r) * 64 + ct * 16 + row));
            out_e[(size_t)eg4[r] * 64 + ct * 16 + row] = leaky(eav + a2[ct][r]);
        }
}

extern "C" void kernel_launch(void* const* d_in, const int* in_sizes, int n_in,
                              void* d_out, int out_size, void* d_ws, size_t ws_size,
                              hipStream_t stream)
{
    const float* x  = (const float*)d_in[0];
    const int*   ei = (const int*)d_in[1];
    const float* ea = (const float*)d_in[2];
    const float* Wq = (const float*)d_in[3];
    const float* bq = (const float*)d_in[4];
    const float* Wk = (const float*)d_in[5];
    const float* bk = (const float*)d_in[6];
    const float* Wv = (const float*)d_in[7];
    const float* bv = (const float*)d_in[8];
    const float* We = (const float*)d_in[9];
    const float* Ws = (const float*)d_in[10];
    const float* bs = (const float*)d_in[11];
    const float* W1 = (const float*)d_in[12];
    const float* b1 = (const float*)d_in[13];
    const float* W2 = (const float*)d_in[14];
    const float* b2 = (const float*)d_in[15];

    char* ws = (char*)d_ws;
    int*   flags  = (int*)ws;                       // 4 KB
    int*   ssort  = (int*)(ws + 4096);
    int*   dsort  = (int*)(ws + 1604096);
    int*   eids   = (int*)(ws + 3204096);
    int*   cursor = (int*)(ws + 4804096);           // end-pointers after kct
    bf16*  WeTf   = (bf16*)(ws + 5004096);          // 32 KB
    bf16*  W1sdf  = (bf16*)(ws + 5036864);          // 64 KB
    bf16*  W1eaf  = (bf16*)(ws + 5102400);          // 8 KB
    bf16*  W2Tf   = (bf16*)(ws + 5110592);          // 8 KB
    bf16*  WT4f   = (bf16*)(ws + 5118784);          // 512 KB
    bf16*  qb     = (bf16*)(ws + 5643072);          // 25.6 MB
    bf16*  kvb    = (bf16*)(ws + 31243072);         // 51.2 MB (k|v interleaved)
    bf16*  easb   = (bf16*)(ws + 82443072);         // 51.2 MB (sorted ea bf16)
    bf16*  Pp     = (bf16*)(ws + 133643072);        // node projections (12.8 MB, ends 146.4M)

    float* out_x = (float*)d_out;
    float* out_e = out_x + (size_t)N_NODES * D_NODE;
    bf16*  skipb = (bf16*)out_e;   // bf16 skip staged in edge-out region

    hipMemsetAsync(cursor, 0, N_NODES * 4, stream);       // degree counters

    k0_detect<<<1, 64, 0, stream>>>(ei, flags);
    kcd_degree<<<(N_EDGES + 255) / 256, 256, 0, stream>>>(ei, flags, cursor);
    kcs_scan<<<1, 1024, 0, stream>>>(cursor);
    kct_scatter<<<(N_EDGES + 255) / 256, 256, 0, stream>>>(
        ei, flags, cursor, ea, ssort, dsort, eids, easb);

    kT_transpose<<<64, 256, 0, stream>>>(We, W1, W2, Wq, Wk, Wv, Ws,
                                         WeTf, W1sdf, W1eaf, W2Tf, WT4f);

    k1_node_mfma<<<(N_NODES + 63) / 64, 256, 0, stream>>>(
        x, WT4f, bq, bk, bv, bs, qb, kvb, skipb);

    k2_seg<<<N_NODES / SEG, 256, 0, stream>>>(
        ssort, dsort, cursor, easb, WeTf, qb, kvb, skipb, W1sdf,
        out_x, Pp);

    k4_edge_mlp<<<N_EDGES / 64, 256, 0, stream>>>(
        ssort, dsort, eids, Pp, easb, W1eaf, b1, W2Tf, b2, out_e);
}

// Round 24
// 558.342 us; speedup vs baseline: 1.0661x; 1.0661x over previous
//
#include <hip/hip_runtime.h>
#include <hip/hip_bf16.h>

// GCNBlock: TransformerConv(32 heads, dim 8, edge_dim 64) + EdgeResidualLayer
// N=50000, E=400000, D_NODE=256, D_EDGE=64. FP32 in/out, int64 edge_index.
// Internals: bf16 MFMA (16x16x32) with fp32 accumulate.
//
// Round 24: exact revert to round-21 (best: 561.9us). Rounds 22/23 proved
// sorted-ea rematerialization is net-negative in every producer placement
// (random ea[eidsort] permutation costs ~50us wherever paid; k2's consumer
// win is only ~20us). Config: k4 P-vectorization (r21), kv-interleave (r20),
// fused finalize+P-GEMM in k2 (r18), fragment-major B layouts (r15), CSR
// dst-sort, barrier-free k1/k2, k4 XCD swizzle, nt loads, cached stores.

#define N_NODES 50000
#define N_EDGES 400000
#define D_NODE 256
#define D_EDGE 64
#define HEADS 32
#define LRELU 0.01f
#define SEG 16          // dst nodes per k2 block

typedef __hip_bfloat16 bf16;
typedef __attribute__((ext_vector_type(8))) short short8b;          // 8 bf16
typedef __attribute__((ext_vector_type(4))) float f32x4;
typedef __attribute__((ext_vector_type(4))) unsigned short ushort4v;
typedef __attribute__((ext_vector_type(4))) int int4v;

__device__ __forceinline__ float bf2f(bf16 v) { return __bfloat162float(v); }
__device__ __forceinline__ bf16 f2bf(float f) { return __float2bfloat16(f); }
__device__ __forceinline__ float bfraw(unsigned short u) {
    return __uint_as_float(((unsigned int)u) << 16);
}
__device__ __forceinline__ unsigned short rawbf(float f) {
    bf16 t = f2bf(f); return *(unsigned short*)&t;
}
__device__ __forceinline__ float leaky(float v) { return v >= 0.f ? v : LRELU * v; }
__device__ __forceinline__ short8b pack8(const f32x4 a, const f32x4 b) {
    short8b r;
    r[0] = (short)rawbf(a[0]); r[1] = (short)rawbf(a[1]);
    r[2] = (short)rawbf(a[2]); r[3] = (short)rawbf(a[3]);
    r[4] = (short)rawbf(b[0]); r[5] = (short)rawbf(b[1]);
    r[6] = (short)rawbf(b[2]); r[7] = (short)rawbf(b[3]);
    return r;
}

// ---------------- k0: index width detection (1 wave) ----------------
__global__ void k0_detect(const int* __restrict__ ei, int* __restrict__ flags)
{
    const int lane = threadIdx.x;
    const unsigned long long mz = __ballot(ei[2 * lane + 1] == 0);
    if (lane == 0) flags[0] = (__popcll(mz) >= 48) ? 1 : 0;   // 1 => int64
}

__device__ __forceinline__ void load_edge(const int* ei, int f, int i, int& s, int& d)
{
    if (f) {
        const long long* e64 = (const long long*)ei;
        s = (int)e64[i]; d = (int)e64[N_EDGES + i];
    } else {
        s = ei[i]; d = ei[N_EDGES + i];
    }
}

// ---------------- CSR build ----------------
__global__ __launch_bounds__(256) void kcd_degree(
    const int* __restrict__ ei, const int* __restrict__ flags, int* __restrict__ deg)
{
    const int i = blockIdx.x * 256 + threadIdx.x;
    if (i >= N_EDGES) return;
    int s, d; load_edge(ei, flags[0], i, s, d);
    atomicAdd(&deg[d], 1);
}

__global__ __launch_bounds__(1024) void kcs_scan(int* __restrict__ cur)  // deg -> excl. offsets
{
    __shared__ int ps[1024];
    const int t = threadIdx.x;
    const int CHN = (N_NODES + 1023) / 1024;   // 49
    const int base = t * CHN;
    int sum = 0;
    for (int i = 0; i < CHN; ++i) {
        const int n = base + i;
        if (n < N_NODES) sum += cur[n];
    }
    ps[t] = sum;
    __syncthreads();
    for (int off = 1; off < 1024; off <<= 1) {
        const int v = (t >= off) ? ps[t - off] : 0;
        __syncthreads();
        ps[t] += v;
        __syncthreads();
    }
    int excl = (t == 0) ? 0 : ps[t - 1];
    for (int i = 0; i < CHN; ++i) {
        const int n = base + i;
        if (n < N_NODES) {
            const int d = cur[n];
            cur[n] = excl;
            excl += d;
        }
    }
}

__global__ __launch_bounds__(256) void kct_scatter(
    const int* __restrict__ ei, const int* __restrict__ flags, int* __restrict__ cursor,
    int* __restrict__ ssort, int* __restrict__ dsort, int* __restrict__ eidsort)
{
    const int i = blockIdx.x * 256 + threadIdx.x;
    if (i >= N_EDGES) return;
    int s, d; load_edge(ei, flags[0], i, s, d);
    const int pos = atomicAdd(&cursor[d], 1);
    ssort[pos] = s; dsort[pos] = d; eidsort[pos] = i;
    // after this kernel: cursor[n] == end offset of node n (inclusive)
}

// ---------------- kT: fragment-major weight layouts (fp32 -> bf16) ----------------
__global__ __launch_bounds__(256) void kT_transpose(
    const float* __restrict__ We, const float* __restrict__ W1, const float* __restrict__ W2,
    const float* __restrict__ Wq, const float* __restrict__ Wk,
    const float* __restrict__ Wv, const float* __restrict__ Ws,
    bf16* __restrict__ WeTf, bf16* __restrict__ W1sdf, bf16* __restrict__ W1eaf,
    bf16* __restrict__ W2Tf, bf16* __restrict__ WT4f)
{
    const int gid = blockIdx.x * 256 + threadIdx.x;
    const int gsz = gridDim.x * 256;
    // WT4f: [m(4)][ct(16)][kc(8)][l(64)][j(8)]  (q,k,v,s; 256x256 each)
    for (int i = gid; i < 4 * 16 * 8 * 512; i += gsz) {
        const int j = i & 7, l = (i >> 3) & 63, kc = (i >> 9) & 7;
        const int ct = (i >> 12) & 15, m = i >> 16;
        const int row = l & 15, kg = l >> 4;
        const int n = ct * 16 + row, k = kc * 32 + kg * 8 + j;
        const float* W = (m == 0) ? Wq : (m == 1) ? Wk : (m == 2) ? Wv : Ws;
        WT4f[i] = f2bf(W[k * 256 + n]);
    }
    // WeTf: [ct(16)][kc(2)][l][j]  (We: 64x256)
    for (int i = gid; i < 16 * 2 * 512; i += gsz) {
        const int j = i & 7, l = (i >> 3) & 63, kc = (i >> 9) & 1, ct = i >> 10;
        const int row = l & 15, kg = l >> 4;
        const int n = ct * 16 + row, k = kc * 32 + kg * 8 + j;
        WeTf[i] = f2bf(We[k * 256 + n]);
    }
    // W1sdf: [m2(2)][ct(4)][kc(8)][l][j]  (W1 rows 0..255 = x_s, 256..511 = x_d)
    for (int i = gid; i < 2 * 4 * 8 * 512; i += gsz) {
        const int j = i & 7, l = (i >> 3) & 63, kc = (i >> 9) & 7;
        const int ct = (i >> 12) & 3, m2 = i >> 14;
        const int row = l & 15, kg = l >> 4;
        const int n = ct * 16 + row;
        const int k = m2 * 256 + kc * 32 + kg * 8 + j;
        W1sdf[i] = f2bf(W1[k * 64 + n]);
    }
    // W1eaf: [ct(4)][kc(2)][l][j]  (W1 rows 512..575 = ea)
    for (int i = gid; i < 4 * 2 * 512; i += gsz) {
        const int j = i & 7, l = (i >> 3) & 63, kc = (i >> 9) & 1, ct = i >> 10;
        const int row = l & 15, kg = l >> 4;
        const int n = ct * 16 + row;
        const int k = 512 + kc * 32 + kg * 8 + j;
        W1eaf[i] = f2bf(W1[k * 64 + n]);
    }
    // W2Tf: [ct(4)][kc(2)][l][j]  (W2: 64x64)
    for (int i = gid; i < 4 * 2 * 512; i += gsz) {
        const int j = i & 7, l = (i >> 3) & 63, kc = (i >> 9) & 1, ct = i >> 10;
        const int row = l & 15, kg = l >> 4;
        const int n = ct * 16 + row, k = kc * 32 + kg * 8 + j;
        W2Tf[i] = f2bf(W2[k * 64 + n]);
    }
}

// ---------------- k1: node linears via MFMA (k|v interleaved out) ----------------
#define X_LD 264
__global__ __launch_bounds__(256) void k1_node_mfma(
    const float* __restrict__ x, const bf16* __restrict__ WT4f,
    const float* __restrict__ bq, const float* __restrict__ bk,
    const float* __restrict__ bv, const float* __restrict__ bs,
    bf16* __restrict__ qo, bf16* __restrict__ kvb,
    bf16* __restrict__ skipb)
{
    __shared__ unsigned short xs[64 * X_LD];   // 33792 B; rows wave-private
    const int tid = threadIdx.x;
    const int n0 = blockIdx.x * 64;
    const int w = tid >> 6, l = tid & 63;
    const int row = l & 15, kg = l >> 4;

    { // stage x tile (fp32 -> bf16), nt loads; wave-private rows
        const int e = tid >> 2, t = tid & 3;
        const int nmine = n0 + e;
        const f32x4* src = (const f32x4*)(x + (size_t)nmine * 256 + t * 64);
        #pragma unroll
        for (int c = 0; c < 4; ++c) {
            unsigned short tmp[16];
            if (nmine < N_NODES) {
                #pragma unroll
                for (int u = 0; u < 4; ++u) {
                    const f32x4 v = __builtin_nontemporal_load(src + c * 4 + u);
                    tmp[u * 4 + 0] = rawbf(v[0]); tmp[u * 4 + 1] = rawbf(v[1]);
                    tmp[u * 4 + 2] = rawbf(v[2]); tmp[u * 4 + 3] = rawbf(v[3]);
                }
            } else {
                #pragma unroll
                for (int u = 0; u < 16; ++u) tmp[u] = 0;
            }
            *(short8b*)&xs[e * X_LD + t * 64 + c * 16]     = *(short8b*)&tmp[0];
            *(short8b*)&xs[e * X_LD + t * 64 + c * 16 + 8] = *(short8b*)&tmp[8];
        }
    }
    // same-wave DS ops are in-order: staging writes precede these reads
    short8b af[8];
    #pragma unroll
    for (int kc = 0; kc < 8; ++kc)
        af[kc] = *(const short8b*)&xs[(w * 16 + row) * X_LD + kc * 32 + kg * 8];

    for (int m = 0; m < 4; ++m) {
        const float* bias = (m == 0) ? bq : (m == 1) ? bk : (m == 2) ? bv : bs;
        #pragma unroll 4
        for (int ct = 0; ct < 16; ++ct) {
            const float bvv = bias[ct * 16 + row];
            f32x4 acc = {bvv, bvv, bvv, bvv};
            #pragma unroll
            for (int kc = 0; kc < 8; ++kc) {
                const short8b bfr = *(const short8b*)(WT4f + (((size_t)((m * 16 + ct) * 8 + kc)) << 9) + l * 8);
                acc = __builtin_amdgcn_mfma_f32_16x16x32_bf16(af[kc], bfr, acc, 0, 0, 0);
            }
            #pragma unroll
            for (int r = 0; r < 4; ++r)   // bounce into this wave's own rows
                xs[(w * 16 + kg * 4 + r) * X_LD + ct * 16 + row] = rawbf(acc[r]);
        }
        { // per-wave cached store: each instruction writes 1KB contiguous
            #pragma unroll
            for (int u = 0; u < 8; ++u) {
                const int flat = u * 64 + l;          // 16B unit in wave's 8KB
                const int node = w * 16 + (flat >> 5);
                const int col8 = (flat & 31) * 8;
                if (n0 + node < N_NODES) {
                    const short8b vdat = *(const short8b*)&xs[node * X_LD + col8];
                    bf16* dp;
                    if (m == 0)      dp = qo    + (size_t)(n0 + node) * 256 + col8;
                    else if (m == 1) dp = kvb   + (size_t)(n0 + node) * 512 + col8;        // k half
                    else if (m == 2) dp = kvb   + (size_t)(n0 + node) * 512 + 256 + col8;  // v half
                    else             dp = skipb + (size_t)(n0 + node) * 256 + col8;
                    *(short8b*)dp = vdat;
                }
            }
        }
        // no barrier: same-wave DS in-order; waves never share rows
    }
}

// ---------------- k2: segment attention + fused finalize + fused P-GEMM ----------------
#define EP_LD 264
__global__ __launch_bounds__(256) void k2_seg(
    const int* __restrict__ ssort, const int* __restrict__ dsort,
    const int* __restrict__ eidsort, const int* __restrict__ endptr,
    const float* __restrict__ ea, const bf16* __restrict__ WeTf,
    const bf16* __restrict__ q, const bf16* __restrict__ kvb,
    const bf16* __restrict__ skipb, const bf16* __restrict__ W1sdf,
    float* __restrict__ out_x, bf16* __restrict__ P)
{
    __shared__ float acc_s[SEG * 256];            // 16 KB msg accumulator
    __shared__ float den_s[SEG * HEADS];          // 2 KB
    __shared__ unsigned short ep_s[64 * EP_LD];   // 33 KB (wave-private rows; reused for xn)
    const int tid = threadIdx.x;
    const int n0 = blockIdx.x * SEG;

    #pragma unroll
    for (int i = 0; i < SEG; ++i) acc_s[i * 256 + tid] = 0.f;
    if (tid < SEG * HEADS - 256) den_s[256 + tid] = 0.f;
    den_s[tid] = 0.f;

    const int start = (n0 == 0) ? 0 : endptr[n0 - 1];
    const int end   = endptr[n0 + SEG - 1];
    __syncthreads();

    const int w = tid >> 6, l = tid & 63;
    const int row = l & 15, kg = l >> 4;
    const float scale = 0.35355339059327373f;   // 1/sqrt(8)

    // each wave free-runs its own 16-edge slices; no barriers in this loop
    for (int sbase = start + w * 16; sbase < end; sbase += 64) {
        const int cnt = min(16, end - sbase);   // >= 1

        // --- A fragments direct from global ea (fp32 -> bf16 in regs) ---
        short8b af0 = {0, 0, 0, 0, 0, 0, 0, 0}, af1 = af0;
        if (row < cnt) {
            const int eg = eidsort[sbase + row];
            const float* pb = ea + (size_t)eg * 64 + kg * 8;
            const f32x4 a0 = __builtin_nontemporal_load((const f32x4*)pb);
            const f32x4 a1 = __builtin_nontemporal_load((const f32x4*)(pb + 4));
            const f32x4 b0 = __builtin_nontemporal_load((const f32x4*)(pb + 32));
            const f32x4 b1 = __builtin_nontemporal_load((const f32x4*)(pb + 36));
            af0 = pack8(a0, a1); af1 = pack8(b0, b1);
        }

        // --- edge indices for this wave's slice ---
        int sv = 0;
        if (l < 16)      { if (l < cnt)      sv = ssort[sbase + l]; }
        else if (l < 32) { if (l - 16 < cnt) sv = dsort[sbase + (l - 16)]; }

        // --- prefetch k/v slices from interleaved kvb (one 1KB row / edge) ---
        ushort4v kvv[16], vvv[16];
        #pragma unroll
        for (int i = 0; i < 16; ++i) {
            const int s = __shfl(sv, min(i, cnt - 1));
            const bf16* base = kvb + (size_t)s * 512;
            kvv[i] = *(const ushort4v*)(base + l * 4);
            vvv[i] = *(const ushort4v*)(base + 256 + l * 4);
        }
        __builtin_amdgcn_sched_barrier(0);   // pin: all gathers issued

        // --- eproj MFMA into wave-private ep rows (coalesced B) ---
        #pragma unroll 4
        for (int ct = 0; ct < 16; ++ct) {
            f32x4 acc = {0.f, 0.f, 0.f, 0.f};
            const short8b b0 = *(const short8b*)(WeTf + (ct * 2 + 0) * 512 + l * 8);
            const short8b b1 = *(const short8b*)(WeTf + (ct * 2 + 1) * 512 + l * 8);
            acc = __builtin_amdgcn_mfma_f32_16x16x32_bf16(af0, b0, acc, 0, 0, 0);
            acc = __builtin_amdgcn_mfma_f32_16x16x32_bf16(af1, b1, acc, 0, 0, 0);
            #pragma unroll
            for (int r = 0; r < 4; ++r)
                ep_s[(w * 16 + kg * 4 + r) * EP_LD + ct * 16 + row] = rawbf(acc[r]);
        }
        // same-wave LDS write->read is in-order: no barrier needed

        // --- attention (run-compressed); q loaded per run ---
        float macc[4] = {0.f, 0.f, 0.f, 0.f};
        float dacc = 0.f;
        int dprev = -1;
        ushort4v qv = {0, 0, 0, 0};

        #pragma unroll
        for (int i = 0; i < 16; ++i) {
            const int d = __shfl(sv, 16 + min(i, cnt - 1));
            if (d != dprev) {                  // wave-uniform
                if (dprev >= 0) {
                    const int ld = dprev - n0;
                    #pragma unroll
                    for (int t = 0; t < 4; ++t)
                        atomicAdd(&acc_s[ld * 256 + l * 4 + t], macc[t]);
                    if ((l & 1) == 0)
                        atomicAdd(&den_s[ld * HEADS + (l >> 1)], dacc);
                    macc[0] = macc[1] = macc[2] = macc[3] = 0.f;
                    dacc = 0.f;
                }
                qv = *(const ushort4v*)(q + (size_t)d * 256 + l * 4);
                dprev = d;
            }
            const ushort4v ep = *(const ushort4v*)&ep_s[(w * 16 + i) * EP_LD + l * 4];
            float p = 0.f, m4[4];
            #pragma unroll
            for (int t = 0; t < 4; ++t) {
                const float epf = bfraw(ep[t]);
                p = fmaf(bfraw(qv[t]), bfraw(kvv[i][t]) + epf, p);
                m4[t] = bfraw(vvv[i][t]) + epf;
            }
            p += __shfl_xor(p, 1);             // head = l>>1 (2 lanes/head)
            const float ex = (i < cnt) ? __expf(p * scale) : 0.f;
            #pragma unroll
            for (int t = 0; t < 4; ++t) macc[t] = fmaf(m4[t], ex, macc[t]);
            dacc += ex;
        }
        {
            const int ld = dprev - n0;
            #pragma unroll
            for (int t = 0; t < 4; ++t)
                atomicAdd(&acc_s[ld * 256 + l * 4 + t], macc[t]);
            if ((l & 1) == 0)
                atomicAdd(&den_s[ld * HEADS + (l >> 1)], dacc);
        }
    }
    __syncthreads();   // all waves' aggregation done; ep_s free for reuse

    // finalize: x_new = leaky(acc/den + skip) -> out_x fp32;
    // xn bf16 stashed in ep_s rows [node][ch] for the fused P-GEMM.
    #pragma unroll
    for (int u = 0; u < 4; ++u) {
        const int flat4 = u * 256 + tid;        // f32x4 unit; 64 per node
        const int node = flat4 >> 6;
        const int ch4 = flat4 & 63;
        const int n = n0 + node;
        const float den = den_s[node * HEADS + (ch4 >> 1)] + 1e-16f;
        const f32x4 mv = *(const f32x4*)&acc_s[node * 256 + ch4 * 4];
        const ushort4v sk = *(const ushort4v*)(skipb + (size_t)n * 256 + ch4 * 4);
        f32x4 o; ushort4v ob;
        #pragma unroll
        for (int t = 0; t < 4; ++t) {
            const float xn = leaky(mv[t] / den + bfraw(sk[t]));
            o[t] = xn; ob[t] = rawbf(xn);
        }
        *(f32x4*)(out_x + (size_t)n * 256 + ch4 * 4) = o;
        *(ushort4v*)&ep_s[node * EP_LD + ch4 * 4] = ob;
    }
    __syncthreads();

    // fused P-GEMM (was k3b): P[n] = [xn@W1_s | xn@W1_d]; 8 ct tiles / 4 waves
    // P layout (k4-optimized): P[n][m2*64 + row*4 + ct4] -- each k4 lane's 4
    // values are one contiguous 8B ushort4.
    {
        short8b af2[8];
        #pragma unroll
        for (int kc = 0; kc < 8; ++kc)
            af2[kc] = *(const short8b*)&ep_s[row * EP_LD + kc * 32 + kg * 8];
        #pragma unroll
        for (int c2 = 0; c2 < 2; ++c2) {
            const int ct = w * 2 + c2;            // 0..7 over 128 P columns
            const int m2 = ct >> 2, ct4 = ct & 3;
            f32x4 acc = {0.f, 0.f, 0.f, 0.f};
            #pragma unroll
            for (int kc = 0; kc < 8; ++kc) {
                const short8b bfr = *(const short8b*)(W1sdf + ((m2 * 4 + ct4) * 8 + kc) * 512 + l * 8);
                acc = __builtin_amdgcn_mfma_f32_16x16x32_bf16(af2[kc], bfr, acc, 0, 0, 0);
            }
            #pragma unroll
            for (int r = 0; r < 4; ++r)
                P[(size_t)(n0 + kg * 4 + r) * 128 + m2 * 64 + row * 4 + ct4] = f2bf(acc[r]);
        }
    }
}

// ---------------- k4: edge MLP, vectorized gathers (int4 indices, ushort4 P) ----------------
__global__ __launch_bounds__(256) void k4_edge_mlp(
    const int* __restrict__ ssort, const int* __restrict__ dsort,
    const int* __restrict__ eidsort,
    const bf16* __restrict__ P, const float* __restrict__ ea,
    const bf16* __restrict__ W1eaf, const float* __restrict__ b1,
    const bf16* __restrict__ W2Tf, const float* __restrict__ b2,
    float* __restrict__ out_e)
{
    __shared__ unsigned short h2_s[4][16 * 72];   // 9216 B, wave-private
    __shared__ unsigned short ea_s[4][16 * 72];   // 9216 B, wave-private ea stash
    const int tid = threadIdx.x;
    const int w = tid >> 6, l = tid & 63;
    const int row = l & 15, kg = l >> 4;

    // bijective XCD swizzle (T1, m204): nwg=6250, q8=781, r8=2
    const int q8 = (N_EDGES / 64) >> 3, r8 = (N_EDGES / 64) & 7;
    const int xcd = blockIdx.x & 7, idx = blockIdx.x >> 3;
    const int bid = (xcd < r8 ? xcd * (q8 + 1) : r8 * (q8 + 1) + (xcd - r8) * q8) + idx;
    const int e0 = bid * 64;
    const int sl = e0 + w * 16 + row;            // this lane's A-row edge
    const int eg = eidsort[sl];

    // C-row edge indices via int4 (cr0 16B-aligned: e0 mult of 64)
    const int cr0 = e0 + w * 16 + kg * 4;
    const int4v s4  = *(const int4v*)(ssort + cr0);
    const int4v d4  = *(const int4v*)(dsort + cr0);
    const int4v eg4 = *(const int4v*)(eidsort + cr0);

    // ---- issue all loads up front: 4 ea (nt) + 8 P ushort4 gathers ----
    const float* pb = ea + (size_t)eg * 64 + kg * 8;
    const f32x4 a0 = __builtin_nontemporal_load((const f32x4*)pb);
    const f32x4 a1 = __builtin_nontemporal_load((const f32x4*)(pb + 4));
    const f32x4 c0 = __builtin_nontemporal_load((const f32x4*)(pb + 32));
    const f32x4 c1 = __builtin_nontemporal_load((const f32x4*)(pb + 36));

    const unsigned short* Pu = (const unsigned short*)P;
    ushort4v ps4[4], pd4[4];   // ps4[r][ct] = psv[ct][r]
    #pragma unroll
    for (int r = 0; r < 4; ++r) {
        ps4[r] = *(const ushort4v*)(Pu + (size_t)s4[r] * 128 + row * 4);
        pd4[r] = *(const ushort4v*)(Pu + (size_t)d4[r] * 128 + 64 + row * 4);
    }
    __builtin_amdgcn_sched_barrier(0);   // pin: all loads issued before compute

    const short8b afr0 = pack8(a0, a1);
    const short8b afr1 = pack8(c0, c1);
    // stash bf16 ea tile for the residual epilogue (same-wave in-order)
    *(short8b*)&ea_s[w][row * 72 + kg * 8]      = afr0;
    *(short8b*)&ea_s[w][row * 72 + 32 + kg * 8] = afr1;

    // ---- GEMM1: ea part only, [16 x 64] @ W1_ea -> [16 x 64] (coalesced B) ----
    f32x4 acc[4];
    #pragma unroll
    for (int ct = 0; ct < 4; ++ct) {
        const float bvv = b1[ct * 16 + row];
        acc[ct] = (f32x4){bvv, bvv, bvv, bvv};
    }
    #pragma unroll
    for (int kc = 0; kc < 2; ++kc) {
        const short8b af = (kc == 0) ? afr0 : afr1;
        #pragma unroll
        for (int ct = 0; ct < 4; ++ct) {
            const short8b bfr = *(const short8b*)(W1eaf + (ct * 2 + kc) * 512 + l * 8);
            acc[ct] = __builtin_amdgcn_mfma_f32_16x16x32_bf16(af, bfr, acc[ct], 0, 0, 0);
        }
    }
    // add precomputed node projections (ps4[r][ct] layout)
    #pragma unroll
    for (int ct = 0; ct < 4; ++ct)
        #pragma unroll
        for (int r = 0; r < 4; ++r)
            acc[ct][r] += bfraw(ps4[r][ct]) + bfraw(pd4[r][ct]);

    // h2 = leaky(acc) -> wave-private LDS bounce (same-wave in-order)
    unsigned short* h2 = h2_s[w];
    #pragma unroll
    for (int ct = 0; ct < 4; ++ct)
        #pragma unroll
        for (int r = 0; r < 4; ++r)
            h2[(kg * 4 + r) * 72 + ct * 16 + row] = rawbf(leaky(acc[ct][r]));

    // ---- GEMM2: [16 x 64] @ W2 -> [16 x 64] (coalesced B) ----
    f32x4 a2[4];
    #pragma unroll
    for (int ct = 0; ct < 4; ++ct) {
        const float bvv = b2[ct * 16 + row];
        a2[ct] = (f32x4){bvv, bvv, bvv, bvv};
    }
    #pragma unroll
    for (int kc = 0; kc < 2; ++kc) {
        const short8b af = *(const short8b*)&h2[row * 72 + kc * 32 + kg * 8];
        #pragma unroll
        for (int ct = 0; ct < 4; ++ct) {
            const short8b bfr = *(const short8b*)(W2Tf + (ct * 2 + kc) * 512 + l * 8);
            a2[ct] = __builtin_amdgcn_mfma_f32_16x16x32_bf16(af, bfr, a2[ct], 0, 0, 0);
        }
    }

    // epilogue: out = leaky(ea + h2@W2+b2); ea residual from LDS stash
    #pragma unroll
    for (int ct = 0; ct < 4; ++ct)
        #pragma unroll
        for (int r = 0; r < 4; ++r) {
            const float eav = bfraw(ea_s[w][(kg * 4 + r) * 72 + ct * 16 + row]);
            out_e[(size_t)eg4[r] * 64 + ct * 16 + row] = leaky(eav + a2[ct][r]);
        }
}

extern "C" void kernel_launch(void* const* d_in, const int* in_sizes, int n_in,
                              void* d_out, int out_size, void* d_ws, size_t ws_size,
                              hipStream_t stream)
{
    const float* x  = (const float*)d_in[0];
    const int*   ei = (const int*)d_in[1];
    const float* ea = (const float*)d_in[2];
    const float* Wq = (const float*)d_in[3];
    const float* bq = (const float*)d_in[4];
    const float* Wk = (const float*)d_in[5];
    const float* bk = (const float*)d_in[6];
    const float* Wv = (const float*)d_in[7];
    const float* bv = (const float*)d_in[8];
    const float* We = (const float*)d_in[9];
    const float* Ws = (const float*)d_in[10];
    const float* bs = (const float*)d_in[11];
    const float* W1 = (const float*)d_in[12];
    const float* b1 = (const float*)d_in[13];
    const float* W2 = (const float*)d_in[14];
    const float* b2 = (const float*)d_in[15];

    char* ws = (char*)d_ws;
    int*   flags  = (int*)ws;                       // 4 KB
    int*   ssort  = (int*)(ws + 4096);
    int*   dsort  = (int*)(ws + 1604096);
    int*   eids   = (int*)(ws + 3204096);
    int*   cursor = (int*)(ws + 4804096);           // end-pointers after kct
    bf16*  WeTf   = (bf16*)(ws + 5004096);          // 32 KB
    bf16*  W1sdf  = (bf16*)(ws + 5036864);          // 64 KB
    bf16*  W1eaf  = (bf16*)(ws + 5102400);          // 8 KB
    bf16*  W2Tf   = (bf16*)(ws + 5110592);          // 8 KB
    bf16*  WT4f   = (bf16*)(ws + 5118784);          // 512 KB
    bf16*  qb     = (bf16*)(ws + 5643072);          // 25.6 MB
    bf16*  kvb    = (bf16*)(ws + 31243072);         // 51.2 MB (k|v interleaved)
    bf16*  xnb    = (bf16*)(ws + 82443072);         // (unused scratch)
    bf16*  Pp     = (bf16*)(ws + 108100000);        // node projections (12.8 MB)

    float* out_x = (float*)d_out;
    float* out_e = out_x + (size_t)N_NODES * D_NODE;
    bf16*  skipb = (bf16*)out_e;   // bf16 skip staged in edge-out region

    hipMemsetAsync(cursor, 0, N_NODES * 4, stream);       // degree counters

    k0_detect<<<1, 64, 0, stream>>>(ei, flags);
    kcd_degree<<<(N_EDGES + 255) / 256, 256, 0, stream>>>(ei, flags, cursor);
    kcs_scan<<<1, 1024, 0, stream>>>(cursor);
    kct_scatter<<<(N_EDGES + 255) / 256, 256, 0, stream>>>(ei, flags, cursor, ssort, dsort, eids);

    kT_transpose<<<64, 256, 0, stream>>>(We, W1, W2, Wq, Wk, Wv, Ws,
                                         WeTf, W1sdf, W1eaf, W2Tf, WT4f);

    k1_node_mfma<<<(N_NODES + 63) / 64, 256, 0, stream>>>(
        x, WT4f, bq, bk, bv, bs, qb, kvb, skipb);

    k2_seg<<<N_NODES / SEG, 256, 0, stream>>>(
        ssort, dsort, eids, cursor, ea, WeTf, qb, kvb, skipb, W1sdf,
        out_x, Pp);

    k4_edge_mlp<<<N_EDGES / 64, 256, 0, stream>>>(
        ssort, dsort, eids, Pp, ea, W1eaf, b1, W2Tf, b2, out_e);
}